// Round 6
// baseline (202.359 us; speedup 1.0000x reference)
//
#include <hip/hip_runtime.h>

// SpanNER via split-bf16 MFMA, barrier-free L2-streaming GEMMs:
//  k_prep  : hidden->bf16 h/l; A_s,A_e -> B^T bf16 h/l; w_p1 -> B^T bf16 h/l;
//            WE3 rows (H rows 1024..1026); TPAD; LPAD
//  k_g1    : H(bf16 h/l) = hidden @ [A_s|A_e], per-wave 16x32 tiles, no LDS/barriers
//  k_g2    : P1(fp32) = Hext @ w_p1 (same structure) + L dots + LW + PPAD
//  k_stage3: pad fill (512 blks) + span epilogue (765 blks x 2 spans)

typedef unsigned short u16;
typedef __attribute__((ext_vector_type(8))) short bf16x8;
typedef __attribute__((ext_vector_type(8))) unsigned short u16x8;
typedef __attribute__((ext_vector_type(4))) float f32x4;

#define D 768
#define S 256
#define TOTAL 32896
#define NVALID 765
#define NPADROW (TOTAL - NVALID)   // 32131
#define PD 128
#define LOGITS_SZ (2 * TOTAL)      // 65792
#define MROWS 1088

// float ws region
#define WS_P1   0                  // [1088][768] fp32
#define WS_TPAD 835584             // [768]
#define WS_L    836352             // [1024]
#define WS_LW   837376             // [3]
#define WS_LPAD 837379             // [1]
#define WS_PPAD 837380             // [128] (16B aligned)
#define US_BYTE_OFF (837632 * 4)
// ushort (bf16) offsets within region starting at US_BYTE_OFF
#define US_HH  0                   // [1088][768] H hi
#define US_HL  835584              // H lo
#define US_AH  1671168             // [512][768] hidden hi
#define US_AL  2064384             // hidden lo
#define US_B1H 2457600             // [1536][768] [A_s|A_e]^T hi
#define US_B1L 3637248             // lo
#define US_W1H 4816896             // [768][768] w_p1^T hi
#define US_W1L 5406720             // lo

__device__ __forceinline__ u16 f2bf(float v) {
    unsigned u = __float_as_uint(v);
    u += 0x7fffu + ((u >> 16) & 1u);
    return (u16)(u >> 16);
}
__device__ __forceinline__ float bf2f(u16 h) {
    return __uint_as_float(((unsigned)h) << 16);
}

__device__ __forceinline__ void span_iw(int k, int& i, int& w) {
    if (k < 762)      { i = k / 3;  w = k - i * 3; }
    else if (k < 764) { i = 254;    w = k - 762; }
    else              { i = 255;    w = 0; }
}

// ==================== k_prep (673 blocks) ====================
__global__ __launch_bounds__(256) void k_prep(const float* __restrict__ hidden,
                                              const float* __restrict__ width_emb,
                                              const float* __restrict__ w_span,
                                              const float* __restrict__ b_span,
                                              const float* __restrict__ w_cls,
                                              const float* __restrict__ b_cls,
                                              const float* __restrict__ w_p1,
                                              const float* __restrict__ b_p1,
                                              float* __restrict__ ws) {
    u16* us = (u16*)((char*)ws + US_BYTE_OFF);
    const int bid = blockIdx.x, tid = threadIdx.x;
    __shared__ u16 Th[64][72];
    __shared__ u16 Tl[64][72];
    __shared__ float red[256];

    if (bid < 192) {                       // hidden -> Ah/Al bf16
        const int e0 = bid * 2048 + tid * 8;
        float4 v0 = *(const float4*)&hidden[e0];
        float4 v1 = *(const float4*)&hidden[e0 + 4];
        float f[8] = {v0.x, v0.y, v0.z, v0.w, v1.x, v1.y, v1.z, v1.w};
        u16x8 h, l;
        #pragma unroll
        for (int c = 0; c < 8; ++c) {
            u16 hh = f2bf(f[c]);
            h[c] = hh;
            l[c] = f2bf(f[c] - bf2f(hh));
        }
        *(u16x8*)&us[US_AH + e0] = h;
        *(u16x8*)&us[US_AL + e0] = l;
        return;
    }
    const float* tsrc = nullptr;
    u16 *tdh = nullptr, *tdl = nullptr;
    int kb = 0, nb = 0;
    if (bid < 480) {                       // w_span A_s/A_e transpose tiles
        int t2 = bid - 192;
        int g = t2 / 144, rem = t2 % 144;
        kb = rem / 12; nb = rem % 12;
        tsrc = w_span + (size_t)g * D * D;
        tdh = us + US_B1H + (size_t)g * D * D;
        tdl = us + US_B1L + (size_t)g * D * D;
    } else if (bid < 624) {                // w_p1 transpose tiles
        int t3 = bid - 480;
        kb = t3 / 12; nb = t3 % 12;
        tsrc = w_p1;
        tdh = us + US_W1H;
        tdl = us + US_W1L;
    }
    if (tsrc) {
        #pragma unroll
        for (int r4 = 0; r4 < 4; ++r4) {
            const int srow = r4 * 16 + (tid >> 4);
            const int scol = (tid & 15) * 4;
            float4 v = *(const float4*)&tsrc[(size_t)(kb * 64 + srow) * D + nb * 64 + scol];
            float f[4] = {v.x, v.y, v.z, v.w};
            #pragma unroll
            for (int c = 0; c < 4; ++c) {
                u16 hh = f2bf(f[c]);
                Th[scol + c][srow] = hh;
                Tl[scol + c][srow] = f2bf(f[c] - bf2f(hh));
            }
        }
        __syncthreads();
        const int orow = tid >> 2, kp = (tid & 3) * 16;
        const size_t didx = (size_t)(nb * 64 + orow) * D + kb * 64 + kp;
        *(u16x8*)&tdh[didx]     = *(const u16x8*)&Th[orow][kp];
        *(u16x8*)&tdh[didx + 8] = *(const u16x8*)&Th[orow][kp + 8];
        *(u16x8*)&tdl[didx]     = *(const u16x8*)&Tl[orow][kp];
        *(u16x8*)&tdl[didx + 8] = *(const u16x8*)&Tl[orow][kp + 8];
        return;
    }
    const int dl = tid & 63, kc = tid >> 6;
    if (bid < 660) {                       // WE3[w] -> H rows 1024..1026 (h/l)
        const int t4 = bid - 624;
        const int w = t4 / 12, seg = t4 % 12;
        const int d = seg * 64 + dl;
        const float* Aw = w_span + (size_t)(2 * D) * D;
        const float* we = width_emb + w * D;
        float p = 0.f;
        #pragma unroll 4
        for (int k = kc * 192; k < kc * 192 + 192; ++k)
            p = fmaf(we[k], Aw[(size_t)k * D + d], p);
        red[tid] = p; __syncthreads();
        if (kc == 0) {
            float v = red[dl] + red[64 + dl] + red[128 + dl] + red[192 + dl] + b_span[d];
            u16 hh = f2bf(v);
            const size_t idx = (size_t)(1024 + w) * D + d;
            us[US_HH + idx] = hh;
            us[US_HL + idx] = f2bf(v - bf2f(hh));
        }
    } else if (bid < 672) {                // TPAD = relu(b_span@w_p1 + b_p1)
        const int d = (bid - 660) * 64 + dl;
        float p = 0.f;
        #pragma unroll 4
        for (int k = kc * 192; k < kc * 192 + 192; ++k)
            p = fmaf(b_span[k], w_p1[(size_t)k * D + d], p);
        red[tid] = p; __syncthreads();
        if (kc == 0) {
            float v = red[dl] + red[64 + dl] + red[128 + dl] + red[192 + dl] + b_p1[d];
            ws[WS_TPAD + d] = fmaxf(v, 0.f);
        }
    } else {                               // LPAD = b_span . w_cls + b_cls
        if (tid < 64) {
            float a = 0.f;
            #pragma unroll
            for (int i = 0; i < 12; ++i) a = fmaf(b_span[tid + 64 * i], w_cls[tid + 64 * i], a);
            for (int off = 32; off > 0; off >>= 1) a += __shfl_down(a, off, 64);
            if (tid == 0) ws[WS_LPAD] = a + b_cls[0];
        }
    }
}

#define MFMA(A, B, C) __builtin_amdgcn_mfma_f32_16x16x32_bf16(A, B, C, 0, 0, 0)
#define LD8(P) (*(const bf16x8*)(P))

// ==================== k_g1 (384 blocks): H = hidden @ [A_s|A_e] ====================
// per-wave 16x32 tile, no LDS, no barriers; operands streamed from L2.
__global__ __launch_bounds__(256) void k_g1(float* __restrict__ ws) {
    u16* us = (u16*)((char*)ws + US_BYTE_OFF);
    const int wid = blockIdx.x * 4 + (threadIdx.x >> 6);   // 0..1535
    const int lane = threadIdx.x & 63;
    const int mt = wid & 31, nt = wid >> 5;                // 32 x 48
    const int m0 = mt * 16, n0 = nt * 32;
    const int lr = lane & 15, lk8 = (lane >> 4) * 8;
    const u16* Ah = us + US_AH; const u16* Al = us + US_AL;
    const u16* Bh = us + US_B1H; const u16* Bl = us + US_B1L;
    const size_t aoff = (size_t)(m0 + lr) * D + lk8;
    const size_t b0 = (size_t)(n0 + lr) * D + lk8;
    const size_t b1 = b0 + (size_t)16 * D;
    f32x4 acc0 = {0,0,0,0}, acc1 = {0,0,0,0};
    bf16x8 ah = LD8(Ah + aoff), al = LD8(Al + aoff);
    bf16x8 bh0 = LD8(Bh + b0), bl0 = LD8(Bl + b0);
    bf16x8 bh1 = LD8(Bh + b1), bl1 = LD8(Bl + b1);
    for (int kt = 0; kt < 24; ++kt) {
        bf16x8 cah = ah, cal = al, cbh0 = bh0, cbl0 = bl0, cbh1 = bh1, cbl1 = bl1;
        if (kt < 23) {
            const size_t o = (size_t)(kt + 1) * 32;
            ah = LD8(Ah + aoff + o); al = LD8(Al + aoff + o);
            bh0 = LD8(Bh + b0 + o);  bl0 = LD8(Bl + b0 + o);
            bh1 = LD8(Bh + b1 + o);  bl1 = LD8(Bl + b1 + o);
        }
        acc0 = MFMA(cah, cbh0, acc0);
        acc0 = MFMA(cah, cbl0, acc0);
        acc0 = MFMA(cal, cbh0, acc0);
        acc1 = MFMA(cah, cbh1, acc1);
        acc1 = MFMA(cah, cbl1, acc1);
        acc1 = MFMA(cal, cbh1, acc1);
    }
    // epilogue: C frag col=lane&15, row=(lane>>4)*4+r; H row = g*512+m, col = n-g*768
    const int g = (n0 >= D);
    const int cb = n0 - g * D;
    const int row0 = g * 512 + m0 + (lane >> 4) * 4;
    u16* Hh = us + US_HH; u16* Hl = us + US_HL;
    #pragma unroll
    for (int r = 0; r < 4; ++r) {
        const size_t base = (size_t)(row0 + r) * D;
        float v0 = acc0[r], v1 = acc1[r];
        u16 h0 = f2bf(v0), h1 = f2bf(v1);
        Hh[base + cb + lr] = h0;       Hl[base + cb + lr] = f2bf(v0 - bf2f(h0));
        Hh[base + cb + 16 + lr] = h1;  Hl[base + cb + 16 + lr] = f2bf(v1 - bf2f(h1));
    }
}

// ==================== k_g2 (424 blocks): P1 = Hext @ w_p1; L; LW; PPAD ====================
__global__ __launch_bounds__(256) void k_g2(const float* __restrict__ w_cls,
                                            const float* __restrict__ b_cls,
                                            const float* __restrict__ w_p2,
                                            const float* __restrict__ b_p2,
                                            float* __restrict__ ws) {
    u16* us = (u16*)((char*)ws + US_BYTE_OFF);
    const int bid = blockIdx.x, tid = threadIdx.x;
    const u16* Hh = us + US_HH; const u16* Hl = us + US_HL;
    if (bid < 390) {
        const int wid = bid * 4 + (tid >> 6);              // 0..1559
        const int lane = tid & 63;
        const int mt = wid % 65, nt = wid / 65;            // 65 x 24
        const int m0 = mt * 16, n0 = nt * 32;
        const int lr = lane & 15, lk8 = (lane >> 4) * 8;
        const u16* Bh = us + US_W1H; const u16* Bl = us + US_W1L;
        const size_t aoff = (size_t)(m0 + lr) * D + lk8;
        const size_t b0 = (size_t)(n0 + lr) * D + lk8;
        const size_t b1 = b0 + (size_t)16 * D;
        f32x4 acc0 = {0,0,0,0}, acc1 = {0,0,0,0};
        bf16x8 ah = LD8(Hh + aoff), al = LD8(Hl + aoff);
        bf16x8 bh0 = LD8(Bh + b0), bl0 = LD8(Bl + b0);
        bf16x8 bh1 = LD8(Bh + b1), bl1 = LD8(Bl + b1);
        for (int kt = 0; kt < 24; ++kt) {
            bf16x8 cah = ah, cal = al, cbh0 = bh0, cbl0 = bl0, cbh1 = bh1, cbl1 = bl1;
            if (kt < 23) {
                const size_t o = (size_t)(kt + 1) * 32;
                ah = LD8(Hh + aoff + o); al = LD8(Hl + aoff + o);
                bh0 = LD8(Bh + b0 + o);  bl0 = LD8(Bl + b0 + o);
                bh1 = LD8(Bh + b1 + o);  bl1 = LD8(Bl + b1 + o);
            }
            acc0 = MFMA(cah, cbh0, acc0);
            acc0 = MFMA(cah, cbl0, acc0);
            acc0 = MFMA(cal, cbh0, acc0);
            acc1 = MFMA(cah, cbh1, acc1);
            acc1 = MFMA(cah, cbl1, acc1);
            acc1 = MFMA(cal, cbh1, acc1);
        }
        float* P1 = ws + WS_P1;
        const int row0 = m0 + (lane >> 4) * 4;
        #pragma unroll
        for (int r = 0; r < 4; ++r) {
            const size_t base = (size_t)(row0 + r) * D;
            P1[base + n0 + lr] = acc0[r];
            P1[base + n0 + 16 + lr] = acc1[r];
        }
    } else if (bid < 422) {
        // L[r] = (Hh[r]+Hl[r]) . w_cls     (1024 rows over 32 blocks)
        const int w64 = tid >> 6, lane = tid & 63;
        const int rbase = (bid - 390) * 32 + w64 * 8;
        for (int rr = 0; rr < 8; ++rr) {
            const int r = rbase + rr;
            const u16* hh = Hh + (size_t)r * D;
            const u16* hl = Hl + (size_t)r * D;
            float a = 0.f;
            #pragma unroll
            for (int i = 0; i < 12; ++i) {
                const int d = lane + 64 * i;
                a = fmaf(bf2f(hh[d]) + bf2f(hl[d]), w_cls[d], a);
            }
            for (int off = 32; off > 0; off >>= 1) a += __shfl_down(a, off, 64);
            if (lane == 0) ws[WS_L + r] = a;
        }
    } else if (bid == 422) {
        // LW[w] = WE3[w] . w_cls + b_cls
        if (tid < 192) {
            const int w = tid >> 6, lane = tid & 63;
            const u16* hh = Hh + (size_t)(1024 + w) * D;
            const u16* hl = Hl + (size_t)(1024 + w) * D;
            float a = 0.f;
            #pragma unroll
            for (int i = 0; i < 12; ++i) {
                const int d = lane + 64 * i;
                a = fmaf(bf2f(hh[d]) + bf2f(hl[d]), w_cls[d], a);
            }
            for (int off = 32; off > 0; off >>= 1) a += __shfl_down(a, off, 64);
            if (lane == 0) ws[WS_LW + w] = a + b_cls[0];
        }
    } else {
        // PPAD = TPAD @ w_p2 + b_p2
        __shared__ float redp[128];
        const int j = tid & 127, h2 = tid >> 7;
        float acc = 0.f;
        #pragma unroll 4
        for (int it = 0; it < 384; ++it) {
            const int d = h2 * 384 + it;
            acc = fmaf(ws[WS_TPAD + d], w_p2[(size_t)d * PD + j], acc);
        }
        if (h2) redp[j] = acc;
        __syncthreads();
        if (!h2) ws[WS_PPAD + j] = acc + redp[j] + b_p2[j];
    }
}

// ==================== k_stage3 (1277 blocks) ====================
__global__ __launch_bounds__(256) void k_stage3(const float* __restrict__ w_p2,
                                                const float* __restrict__ b_p1,
                                                const float* __restrict__ b_p2,
                                                const float* __restrict__ ws,
                                                float* __restrict__ out) {
    const int bid = blockIdx.x, tid = threadIdx.x;
    if (bid < 512) {
        // constant pad fill: logits + 33 MB proj rows
        const int t0 = bid * 256 + tid;
        if (t0 < 2 * NPADROW) {
            int b = t0 / NPADROW;
            out[b * TOTAL + NVALID + (t0 - b * NPADROW)] = ws[WS_LPAD];
        }
        const float4 pp = *(const float4*)&ws[WS_PPAD + ((tid & 31) << 2)];
        float4* out4 = (float4*)(out + LOGITS_SZ);
        const long long totalU = (long long)2 * NPADROW * 32;   // 2056384
        for (long long u = t0; u < totalU; u += 131072) {
            int rb = (int)(u >> 5);
            int b = rb / NPADROW;
            int kk = rb - b * NPADROW;
            out4[((size_t)b * TOTAL + NVALID + kk) * 32 + (int)(u & 31)] = pp;
        }
        return;
    }
    // span epilogue: 2 spans per block, 765 blocks, all spans valid
    const int sb = bid - 512;                               // 0..764
    __shared__ float tld[D * 2];
    __shared__ float red[2 * PD];
    const float* P1 = ws + WS_P1;
    {   // phase 1: t = relu(P1s + P1e + P1w + b_p1), layout tld[d*2 + s]
        const int s = tid >> 7, dl = tid & 127;
        const int q = sb * 2 + s;
        const int b = q >= 765;
        const int k = q - 765 * b;
        int i, w; span_iw(k, i, w);
        const size_t rs = (size_t)(b * S + i) * D;
        const size_t re = (size_t)(512 + b * S + i + w) * D;
        const size_t rw = (size_t)(1024 + w) * D;
        #pragma unroll
        for (int p = 0; p < 6; ++p) {
            const int dd = dl + 128 * p;
            float val = P1[rs + dd] + P1[re + dd] + P1[rw + dd] + b_p1[dd];
            tld[dd * 2 + s] = fmaxf(val, 0.f);
        }
    }
    if (tid < 2) {                                          // logits
        const int q2 = sb * 2 + tid;
        const int b2 = q2 >= 765, k2 = q2 - 765 * b2;
        int i2, w2; span_iw(k2, i2, w2);
        out[b2 * TOTAL + k2] = ws[WS_L + b2 * S + i2]
                             + ws[WS_L + 512 + b2 * S + i2 + w2] + ws[WS_LW + w2];
    }
    __syncthreads();
    // phase 2: proj[s][j] = sum_d t[s][d] * w_p2[d][j]  (K-split 2 over h)
    const int j = tid & 127, h = tid >> 7;
    float a0 = 0.f, a1 = 0.f;
    const float* wp = w_p2 + (size_t)h * 384 * PD + j;
    const float* tb = tld + h * 384 * 2;
    #pragma unroll 4
    for (int it = 0; it < 384; ++it) {
        const float wv = wp[(size_t)it * PD];
        a0 = fmaf(wv, tb[it * 2], a0);
        a1 = fmaf(wv, tb[it * 2 + 1], a1);
    }
    if (h) { red[j] = a0; red[PD + j] = a1; }
    __syncthreads();
    if (!h) {
        const float bp = b_p2[j];
        const float v[2] = {a0 + red[j] + bp, a1 + red[PD + j] + bp};
        #pragma unroll
        for (int s4 = 0; s4 < 2; ++s4) {
            const int q2 = sb * 2 + s4;
            const int b2 = q2 >= 765, k2 = q2 - 765 * b2;
            out[LOGITS_SZ + ((size_t)b2 * TOTAL + k2) * PD + j] = v[s4];
        }
    }
}

extern "C" void kernel_launch(void* const* d_in, const int* in_sizes, int n_in,
                              void* d_out, int out_size, void* d_ws, size_t ws_size,
                              hipStream_t stream) {
    const float* hidden    = (const float*)d_in[0];
    const float* width_emb = (const float*)d_in[1];
    const float* w_span    = (const float*)d_in[2];
    const float* b_span    = (const float*)d_in[3];
    const float* w_cls     = (const float*)d_in[4];
    const float* b_cls     = (const float*)d_in[5];
    const float* w_p1      = (const float*)d_in[6];
    const float* b_p1      = (const float*)d_in[7];
    const float* w_p2      = (const float*)d_in[8];
    const float* b_p2      = (const float*)d_in[9];
    float* out = (float*)d_out;
    float* ws  = (float*)d_ws;   // ~15.4 MB used

    k_prep<<<673, 256, 0, stream>>>(hidden, width_emb, w_span, b_span, w_cls, b_cls,
                                    w_p1, b_p1, ws);
    k_g1<<<384, 256, 0, stream>>>(ws);
    k_g2<<<424, 256, 0, stream>>>(w_cls, b_cls, w_p2, b_p2, ws);
    k_stage3<<<1277, 256, 0, stream>>>(w_p2, b_p1, b_p2, ws, out);
}

// Round 8
// 202.251 us; speedup vs baseline: 1.0005x; 1.0005x over previous
//
#include <hip/hip_runtime.h>

// SpanNER, associativity-restructured:
//   G_s = A_s@w_p1, G_e = A_e@w_p1  (weight-only GEMM, bf16 3-term split)
//   P1  = hidden @ [G_s|G_e]        (data GEMM)
//   logits: exact fp32 dots vs cls_g = A_g@w_cls
//   spans:  t = relu(P1_s[i] + P1_e[j] + P1W[w]); proj = t@w_p2+b_p2
// K0: weight conversions (w_p1^T h/l transpose; A_s|A_e h/l copy)
// K_A: G^T GEMM (576 blk) + hidden->bf16 (192) + cls dots (96) + WE3 (36) + TPAD (12) + LPAD
// K_B: P1 GEMM (384) + L dots (32) + P1W (36) + LW + PPAD
// K_C: pad fill (512) + span epilogue (765 x 2 spans)

typedef unsigned short u16;
typedef __attribute__((ext_vector_type(8))) short bf16x8;
typedef __attribute__((ext_vector_type(8))) unsigned short u16x8;
typedef __attribute__((ext_vector_type(4))) float f32x4;

#define D 768
#define S 256
#define TOTAL 32896
#define NVALID 765
#define NPADROW (TOTAL - NVALID)   // 32131
#define PD 128
#define LOGITS_SZ (2 * TOTAL)      // 65792

// float ws offsets
#define WS_P1   0                  // [512][1536] fp32
#define WS_WE3  786432             // [3][768]  width_emb@A_w + b_span
#define WS_TPAD 788736             // [768]
#define WS_CLS  789504             // [2][768]  A_s@w_cls, A_e@w_cls
#define WS_L    791040             // [1024]    hidden . cls_{s,e}
#define WS_LW   792064             // [3]
#define WS_LPAD 792067             // [1]
#define WS_PPAD 792068             // [128]
#define WS_P1W  792196             // [3][768]  WE3@w_p1 + b_p1
#define US_BYTE_OFF (794624 * 4)
// u16 (bf16) offsets
#define US_AH   0                  // [512][768] hidden hi
#define US_AL   393216             // lo
#define US_W1TH 786432             // [768][768] w_p1^T hi
#define US_W1TL 1376256            // lo
#define US_BSH  1966080            // [1536][768] A_s|A_e hi (row-major as stored)
#define US_BSL  3145728            // lo
#define US_GTH  4325376            // [1536][768] G^T hi  ([g*768+n][i])
#define US_GTL  5505024            // lo

__device__ __forceinline__ u16 f2bf(float v) {
    unsigned u = __float_as_uint(v);
    u += 0x7fffu + ((u >> 16) & 1u);
    return (u16)(u >> 16);
}
__device__ __forceinline__ float bf2f(u16 h) {
    return __uint_as_float(((unsigned)h) << 16);
}
__device__ __forceinline__ void span_iw(int k, int& i, int& w) {
    if (k < 762)      { i = k / 3;  w = k - i * 3; }
    else if (k < 764) { i = 254;    w = k - 762; }
    else              { i = 255;    w = 0; }
}

#define MFMA(A,B,C) __builtin_amdgcn_mfma_f32_16x16x32_bf16(A,B,C,0,0,0)
#define LD8(P) (*(const bf16x8*)(P))

// ==================== K0 (720 blocks): weight conversions ====================
__global__ __launch_bounds__(256) void k0(const float* __restrict__ w_span,
                                          const float* __restrict__ w_p1,
                                          float* __restrict__ ws) {
    u16* us = (u16*)((char*)ws + US_BYTE_OFF);
    const int bid = blockIdx.x, tid = threadIdx.x;
    if (bid < 144) {       // w_p1 -> w_p1^T h/l via LDS transpose
        __shared__ u16 Th[64][72];
        __shared__ u16 Tl[64][72];
        const int kb = bid / 12, nb = bid % 12;
        #pragma unroll
        for (int r4 = 0; r4 < 4; ++r4) {
            const int srow = r4 * 16 + (tid >> 4);
            const int scol = (tid & 15) * 4;
            float4 v = *(const float4*)&w_p1[(size_t)(kb * 64 + srow) * D + nb * 64 + scol];
            float f[4] = {v.x, v.y, v.z, v.w};
            #pragma unroll
            for (int c = 0; c < 4; ++c) {
                u16 hh = f2bf(f[c]);
                Th[scol + c][srow] = hh;
                Tl[scol + c][srow] = f2bf(f[c] - bf2f(hh));
            }
        }
        __syncthreads();
        const int orow = tid >> 2, kp = (tid & 3) * 16;
        const size_t didx = (size_t)(nb * 64 + orow) * D + kb * 64 + kp;
        *(u16x8*)&us[US_W1TH + didx]     = *(const u16x8*)&Th[orow][kp];
        *(u16x8*)&us[US_W1TH + didx + 8] = *(const u16x8*)&Th[orow][kp + 8];
        *(u16x8*)&us[US_W1TL + didx]     = *(const u16x8*)&Tl[orow][kp];
        *(u16x8*)&us[US_W1TL + didx + 8] = *(const u16x8*)&Tl[orow][kp + 8];
    } else {               // A_s|A_e (w_span first 2*D*D elems) -> h/l straight copy
        const int e0 = (bid - 144) * 2048 + tid * 8;
        float4 v0 = *(const float4*)&w_span[e0];
        float4 v1 = *(const float4*)&w_span[e0 + 4];
        float f[8] = {v0.x, v0.y, v0.z, v0.w, v1.x, v1.y, v1.z, v1.w};
        u16x8 h, l;
        #pragma unroll
        for (int c = 0; c < 8; ++c) {
            u16 hh = f2bf(f[c]);
            h[c] = hh;
            l[c] = f2bf(f[c] - bf2f(hh));
        }
        *(u16x8*)&us[US_BSH + e0] = h;
        *(u16x8*)&us[US_BSL + e0] = l;
    }
}

// 3-deep prefetch GEMM building blocks
#define DECLSETS \
    bf16x8 aH0,aL0,b0H0,b0L0,b1H0,b1L0, aH1,aL1,b0H1,b0L1,b1H1,b1L1, aH2,aL2,b0H2,b0L2,b1H2,b1L2;
#define LSET(Sn, KT) { const size_t o_ = (size_t)(KT) * 32; \
    aH##Sn = LD8(pAh + o_); aL##Sn = LD8(pAl + o_); \
    b0H##Sn = LD8(pB0h + o_); b0L##Sn = LD8(pB0l + o_); \
    b1H##Sn = LD8(pB1h + o_); b1L##Sn = LD8(pB1l + o_); }
#define MM6(Sn) { \
    acc0 = MFMA(aH##Sn, b0H##Sn, acc0); acc0 = MFMA(aH##Sn, b0L##Sn, acc0); acc0 = MFMA(aL##Sn, b0H##Sn, acc0); \
    acc1 = MFMA(aH##Sn, b1H##Sn, acc1); acc1 = MFMA(aH##Sn, b1L##Sn, acc1); acc1 = MFMA(aL##Sn, b1H##Sn, acc1); }

// ==================== K_A (913 blocks) ====================
__global__ __launch_bounds__(256) void kA(const float* __restrict__ hidden,
                                          const float* __restrict__ width_emb,
                                          const float* __restrict__ w_span,
                                          const float* __restrict__ b_span,
                                          const float* __restrict__ w_cls,
                                          const float* __restrict__ b_cls,
                                          const float* __restrict__ w_p1,
                                          const float* __restrict__ b_p1,
                                          float* __restrict__ ws) {
    u16* us = (u16*)((char*)ws + US_BYTE_OFF);
    const int bid = blockIdx.x, tid = threadIdx.x;
    if (bid < 576) {
        // G^T[g][n][i] = sum_j w_p1[j,n] * A_g[i,j]  (16n x 32i per wave)
        const int wid = bid * 4 + (tid >> 6);          // 0..2303
        const int lane = tid & 63;
        const int g = wid >= 1152;
        const int w2 = wid - g * 1152;
        const int n0 = (w2 % 48) * 16, i0 = (w2 / 48) * 32;
        const int lr = lane & 15, lk8 = (lane >> 4) * 8;
        const u16* pAh = us + US_W1TH + (size_t)(n0 + lr) * D + lk8;
        const u16* pAl = us + US_W1TL + (size_t)(n0 + lr) * D + lk8;
        const u16* pB0h = us + US_BSH + (size_t)(g * D + i0 + lr) * D + lk8;
        const u16* pB0l = us + US_BSL + (size_t)(g * D + i0 + lr) * D + lk8;
        const u16* pB1h = pB0h + (size_t)16 * D;
        const u16* pB1l = pB0l + (size_t)16 * D;
        f32x4 acc0 = {0,0,0,0}, acc1 = {0,0,0,0};
        DECLSETS
        LSET(0, 0) LSET(1, 1) LSET(2, 2)
        for (int kt = 0; kt < 24; kt += 3) {
            MM6(0)
            if (kt + 3 < 24) LSET(0, kt + 3)
            MM6(1)
            if (kt + 4 < 24) LSET(1, kt + 4)
            MM6(2)
            if (kt + 5 < 24) LSET(2, kt + 5)
        }
        const int nr0 = n0 + (lane >> 4) * 4;
        #pragma unroll
        for (int r = 0; r < 4; ++r) {
            const size_t base = (size_t)(g * D + nr0 + r) * D + i0;
            float v0 = acc0[r], v1 = acc1[r];
            u16 h0 = f2bf(v0), h1 = f2bf(v1);
            us[US_GTH + base + lr] = h0;      us[US_GTL + base + lr] = f2bf(v0 - bf2f(h0));
            us[US_GTH + base + 16 + lr] = h1; us[US_GTL + base + 16 + lr] = f2bf(v1 - bf2f(h1));
        }
    } else if (bid < 768) {
        // hidden -> bf16 h/l
        const int e0 = (bid - 576) * 2048 + tid * 8;
        float4 v0 = *(const float4*)&hidden[e0];
        float4 v1 = *(const float4*)&hidden[e0 + 4];
        float f[8] = {v0.x, v0.y, v0.z, v0.w, v1.x, v1.y, v1.z, v1.w};
        u16x8 h, l;
        #pragma unroll
        for (int c = 0; c < 8; ++c) {
            u16 hh = f2bf(f[c]);
            h[c] = hh;
            l[c] = f2bf(f[c] - bf2f(hh));
        }
        *(u16x8*)&us[US_AH + e0] = h;
        *(u16x8*)&us[US_AL + e0] = l;
    } else if (bid < 864) {
        // cls[rr] = w_span[rr,:] . w_cls   (rr 0..1535)
        const int w64 = tid >> 6, lane = tid & 63;
        #pragma unroll
        for (int q = 0; q < 4; ++q) {
            const int rr = (bid - 768) * 16 + w64 * 4 + q;
            const float* row = w_span + (size_t)rr * D;
            float a = 0.f;
            #pragma unroll
            for (int i = 0; i < 12; ++i) {
                const int d = lane + 64 * i;
                a = fmaf(row[d], w_cls[d], a);
            }
            for (int off = 32; off > 0; off >>= 1) a += __shfl_down(a, off, 64);
            if (lane == 0) ws[WS_CLS + rr] = a;
        }
    } else if (bid < 900) {
        // WE3[w][d] = width_emb[w]@A_w + b_span
        __shared__ float red[256];
        const int dl = tid & 63, kc = tid >> 6;
        const int t4 = bid - 864;
        const int w = t4 / 12, d = (t4 % 12) * 64 + dl;
        const float* Aw = w_span + (size_t)(2 * D) * D;
        const float* we = width_emb + w * D;
        float p = 0.f;
        #pragma unroll 4
        for (int k = kc * 192; k < kc * 192 + 192; ++k)
            p = fmaf(we[k], Aw[(size_t)k * D + d], p);
        red[tid] = p; __syncthreads();
        if (kc == 0)
            ws[WS_WE3 + w * D + d] = red[dl] + red[64 + dl] + red[128 + dl] + red[192 + dl] + b_span[d];
    } else if (bid < 912) {
        // TPAD = relu(b_span@w_p1 + b_p1)
        __shared__ float red[256];
        const int dl = tid & 63, kc = tid >> 6;
        const int d = (bid - 900) * 64 + dl;
        float p = 0.f;
        #pragma unroll 4
        for (int k = kc * 192; k < kc * 192 + 192; ++k)
            p = fmaf(b_span[k], w_p1[(size_t)k * D + d], p);
        red[tid] = p; __syncthreads();
        if (kc == 0)
            ws[WS_TPAD + d] = fmaxf(red[dl] + red[64 + dl] + red[128 + dl] + red[192 + dl] + b_p1[d], 0.f);
    } else {
        // LPAD = b_span . w_cls + b_cls
        if (tid < 64) {
            float a = 0.f;
            #pragma unroll
            for (int i = 0; i < 12; ++i) a = fmaf(b_span[tid + 64 * i], w_cls[tid + 64 * i], a);
            for (int off = 32; off > 0; off >>= 1) a += __shfl_down(a, off, 64);
            if (tid == 0) ws[WS_LPAD] = a + b_cls[0];
        }
    }
}

// ==================== K_B (454 blocks) ====================
__global__ __launch_bounds__(256) void kB(const float* __restrict__ hidden,
                                          const float* __restrict__ w_cls,
                                          const float* __restrict__ b_cls,
                                          const float* __restrict__ w_p1,
                                          const float* __restrict__ b_p1,
                                          const float* __restrict__ w_p2,
                                          const float* __restrict__ b_p2,
                                          float* __restrict__ ws) {
    u16* us = (u16*)((char*)ws + US_BYTE_OFF);
    const int bid = blockIdx.x, tid = threadIdx.x;
    if (bid < 384) {
        // P1[m][n] = hidden[m] @ G (n over 1536), 16m x 32n per wave
        const int wid = bid * 4 + (tid >> 6);          // 0..1535
        const int lane = tid & 63;
        const int m0 = (wid & 31) * 16, n0 = (wid >> 5) * 32;
        const int lr = lane & 15, lk8 = (lane >> 4) * 8;
        const u16* pAh = us + US_AH + (size_t)(m0 + lr) * D + lk8;
        const u16* pAl = us + US_AL + (size_t)(m0 + lr) * D + lk8;
        const u16* pB0h = us + US_GTH + (size_t)(n0 + lr) * D + lk8;
        const u16* pB0l = us + US_GTL + (size_t)(n0 + lr) * D + lk8;
        const u16* pB1h = pB0h + (size_t)16 * D;
        const u16* pB1l = pB0l + (size_t)16 * D;
        f32x4 acc0 = {0,0,0,0}, acc1 = {0,0,0,0};
        DECLSETS
        LSET(0, 0) LSET(1, 1) LSET(2, 2)
        for (int kt = 0; kt < 24; kt += 3) {
            MM6(0)
            if (kt + 3 < 24) LSET(0, kt + 3)
            MM6(1)
            if (kt + 4 < 24) LSET(1, kt + 4)
            MM6(2)
            if (kt + 5 < 24) LSET(2, kt + 5)
        }
        float* P1 = ws + WS_P1;
        const int mr0 = m0 + (lane >> 4) * 4;
        #pragma unroll
        for (int r = 0; r < 4; ++r) {
            const size_t base = (size_t)(mr0 + r) * 1536 + n0;
            P1[base + lr] = acc0[r];
            P1[base + 16 + lr] = acc1[r];
        }
    } else if (bid < 416) {
        // L[rr] = hidden[rr&511] . cls[rr>=512]     (1024 dots)
        const int w64 = tid >> 6, lane = tid & 63;
        const int rbase = (bid - 384) * 32 + w64 * 8;
        for (int rr2 = 0; rr2 < 8; ++rr2) {
            const int rr = rbase + rr2;
            const int g = rr >= 512, r = rr & 511;
            const float* hr = hidden + (size_t)r * D;
            const float* cl = ws + WS_CLS + g * D;
            float a = 0.f;
            #pragma unroll
            for (int i = 0; i < 12; ++i) {
                const int d = lane + 64 * i;
                a = fmaf(hr[d], cl[d], a);
            }
            for (int off = 32; off > 0; off >>= 1) a += __shfl_down(a, off, 64);
            if (lane == 0) ws[WS_L + rr] = a;
        }
    } else if (bid < 452) {
        // P1W[w][d] = WE3[w]@w_p1 + b_p1
        __shared__ float red[256];
        const int dl = tid & 63, kc = tid >> 6;
        const int t4 = bid - 416;
        const int w = t4 / 12, d = (t4 % 12) * 64 + dl;
        const float* we = ws + WS_WE3 + w * D;
        float p = 0.f;
        #pragma unroll 4
        for (int k = kc * 192; k < kc * 192 + 192; ++k)
            p = fmaf(we[k], w_p1[(size_t)k * D + d], p);
        red[tid] = p; __syncthreads();
        if (kc == 0)
            ws[WS_P1W + w * D + d] = red[dl] + red[64 + dl] + red[128 + dl] + red[192 + dl] + b_p1[d];
    } else if (bid == 452) {
        // LW[w] = WE3[w] . w_cls + b_cls
        if (tid < 192) {
            const int w = tid >> 6, lane = tid & 63;
            const float* we = ws + WS_WE3 + w * D;
            float a = 0.f;
            #pragma unroll
            for (int i = 0; i < 12; ++i) {
                const int d = lane + 64 * i;
                a = fmaf(we[d], w_cls[d], a);
            }
            for (int off = 32; off > 0; off >>= 1) a += __shfl_down(a, off, 64);
            if (lane == 0) ws[WS_LW + w] = a + b_cls[0];
        }
    } else {
        // PPAD = TPAD @ w_p2 + b_p2
        __shared__ float redp[128];
        const int j = tid & 127, h2 = tid >> 7;
        float acc = 0.f;
        #pragma unroll 4
        for (int it = 0; it < 384; ++it) {
            const int d = h2 * 384 + it;
            acc = fmaf(ws[WS_TPAD + d], w_p2[(size_t)d * PD + j], acc);
        }
        if (h2) redp[j] = acc;
        __syncthreads();
        if (!h2) ws[WS_PPAD + j] = acc + redp[j] + b_p2[j];
    }
}

// ==================== K_C (1277 blocks) ====================
__global__ __launch_bounds__(256) void kC(const float* __restrict__ w_p2,
                                          const float* __restrict__ b_p2,
                                          const float* __restrict__ ws,
                                          float* __restrict__ out) {
    const int bid = blockIdx.x, tid = threadIdx.x;
    if (bid < 512) {
        const int t0 = bid * 256 + tid;
        if (t0 < 2 * NPADROW) {
            int b = t0 / NPADROW;
            out[b * TOTAL + NVALID + (t0 - b * NPADROW)] = ws[WS_LPAD];
        }
        const float4 pp = *(const float4*)&ws[WS_PPAD + ((tid & 31) << 2)];
        float4* out4 = (float4*)(out + LOGITS_SZ);
        const long long totalU = (long long)2 * NPADROW * 32;   // 2056384
        for (long long u = t0; u < totalU; u += 131072) {
            int rb = (int)(u >> 5);
            int b = rb / NPADROW;
            int kk = rb - b * NPADROW;
            out4[((size_t)b * TOTAL + NVALID + kk) * 32 + (int)(u & 31)] = pp;
        }
        return;
    }
    const int sb = bid - 512;                               // 0..764
    __shared__ float tld[D * 2];
    __shared__ float red[2 * PD];
    const float* P1 = ws + WS_P1;
    {   // phase 1: t = relu(P1_s[i] + P1_e[j] + P1W[w]), layout tld[d*2+s]
        const int s = tid >> 7, dl = tid & 127;
        const int q = sb * 2 + s;
        const int b = q >= 765;
        const int k = q - 765 * b;
        int i, w; span_iw(k, i, w);
        const size_t rs = (size_t)(b * S + i) * 1536;
        const size_t re = (size_t)(b * S + i + w) * 1536 + D;
        const float* pw = ws + WS_P1W + w * D;
        #pragma unroll
        for (int p = 0; p < 6; ++p) {
            const int dd = dl + 128 * p;
            float val = P1[rs + dd] + P1[re + dd] + pw[dd];
            tld[dd * 2 + s] = fmaxf(val, 0.f);
        }
    }
    if (tid < 2) {                                          // logits
        const int q2 = sb * 2 + tid;
        const int b2 = q2 >= 765, k2 = q2 - 765 * b2;
        int i2, w2; span_iw(k2, i2, w2);
        out[b2 * TOTAL + k2] = ws[WS_L + b2 * S + i2]
                             + ws[WS_L + 512 + b2 * S + i2 + w2] + ws[WS_LW + w2];
    }
    __syncthreads();
    const int j = tid & 127, h = tid >> 7;
    float a0 = 0.f, a1 = 0.f;
    const float* wp = w_p2 + (size_t)h * 384 * PD + j;
    const float* tb = tld + h * 384 * 2;
    #pragma unroll 4
    for (int it = 0; it < 384; ++it) {
        const float wv = wp[(size_t)it * PD];
        a0 = fmaf(wv, tb[it * 2], a0);
        a1 = fmaf(wv, tb[it * 2 + 1], a1);
    }
    if (h) { red[j] = a0; red[PD + j] = a1; }
    __syncthreads();
    if (!h) {
        const float bp = b_p2[j];
        const float v[2] = {a0 + red[j] + bp, a1 + red[PD + j] + bp};
        #pragma unroll
        for (int s4 = 0; s4 < 2; ++s4) {
            const int q2 = sb * 2 + s4;
            const int b2 = q2 >= 765, k2 = q2 - 765 * b2;
            out[LOGITS_SZ + ((size_t)b2 * TOTAL + k2) * PD + j] = v[s4];
        }
    }
}

extern "C" void kernel_launch(void* const* d_in, const int* in_sizes, int n_in,
                              void* d_out, int out_size, void* d_ws, size_t ws_size,
                              hipStream_t stream) {
    const float* hidden    = (const float*)d_in[0];
    const float* width_emb = (const float*)d_in[1];
    const float* w_span    = (const float*)d_in[2];
    const float* b_span    = (const float*)d_in[3];
    const float* w_cls     = (const float*)d_in[4];
    const float* b_cls     = (const float*)d_in[5];
    const float* w_p1      = (const float*)d_in[6];
    const float* b_p1      = (const float*)d_in[7];
    const float* w_p2      = (const float*)d_in[8];
    const float* b_p2      = (const float*)d_in[9];
    float* out = (float*)d_out;
    float* ws  = (float*)d_ws;   // ~16.6 MB used

    k0<<<720, 256, 0, stream>>>(w_span, w_p1, ws);
    kA<<<913, 256, 0, stream>>>(hidden, width_emb, w_span, b_span, w_cls, b_cls,
                                w_p1, b_p1, ws);
    kB<<<454, 256, 0, stream>>>(hidden, w_cls, b_cls, w_p1, b_p1, w_p2, b_p2, ws);
    kC<<<1277, 256, 0, stream>>>(w_p2, b_p2, ws, out);
}